// Round 7
// baseline (475.286 us; speedup 1.0000x reference)
//
#include <hip/hip_runtime.h>

namespace {

constexpr int Dn   = 128;
constexpr int DIN  = 512;
constexpr int Hn   = 8;
constexpr int Mn   = 128;
constexpr int DFF  = 512;
constexpr int Gn   = 4;     // batches per block (attention sequential per batch)
constexpr float ATT_SCALE = 0.25f;
constexpr float INV_SQRT2 = 0.70710678118654752440f;

__device__ __forceinline__ unsigned short f2bf(float f) {
    unsigned u = __float_as_uint(f);
    return (unsigned short)((u + 0x7fffu + ((u >> 16) & 1u)) >> 16);
}
__device__ __forceinline__ unsigned pk_bf16(float lo, float hi) {
    unsigned r;
    asm volatile("v_cvt_pk_bf16_f32 %0, %1, %2" : "=v"(r) : "v"(lo), "v"(hi));
    return r;
}
__device__ __forceinline__ float lo16(unsigned u) { return __uint_as_float(u << 16); }
__device__ __forceinline__ float hi16(unsigned u) { return __uint_as_float(u & 0xffff0000u); }

// dot of a 128-float global row with a 128-float LDS vector (broadcast v)
__device__ __forceinline__ float dot128(const float* __restrict__ wrow,
                                        const float* __restrict__ v)
{
    const float4* w4 = (const float4*)wrow;
    const float4* v4 = (const float4*)v;
    float acc = 0.f;
#pragma unroll
    for (int j = 0; j < 32; ++j) {
        float4 a = w4[j], b = v4[j];
        acc += a.x*b.x + a.y*b.y + a.z*b.z + a.w*b.w;
    }
    return acc;
}

// LayerNorm, 64 threads per row (one wave). In-place safe.
template <int NCOL>
__device__ __forceinline__ void ln_row64(const float* __restrict__ src,
                                         float* __restrict__ dst,
                                         const float* __restrict__ gw,
                                         const float* __restrict__ gb,
                                         const float* __restrict__ resid,
                                         int sub)
{
    constexpr int E = NCOL / 64;
    float v0[E]; float sm = 0.f;
#pragma unroll
    for (int i = 0; i < E; ++i) { v0[i] = src[sub*E + i]; sm += v0[i]; }
#pragma unroll
    for (int m = 32; m >= 1; m >>= 1) sm += __shfl_xor(sm, m);
    float mean = sm * (1.f / (float)NCOL);
    float vs = 0.f;
#pragma unroll
    for (int i = 0; i < E; ++i) { float d0 = v0[i] - mean; vs += d0*d0; }
#pragma unroll
    for (int m = 32; m >= 1; m >>= 1) vs += __shfl_xor(vs, m);
    float rstd = rsqrtf(vs * (1.f / (float)NCOL) + 1e-5f);
#pragma unroll
    for (int i = 0; i < E; ++i) {
        int d = sub*E + i;
        float r = (v0[i] - mean) * rstd * gw[d] + gb[d];
        dst[d] = resid ? (r + resid[d]) : r;
    }
}

__global__ __launch_bounds__(256, 3)
void fused_block(const float* __restrict__ x,
                 const float* __restrict__ W_in,
                 const float* __restrict__ b_in,
                 const float* __restrict__ pos,
                 const float* __restrict__ mask,
                 const float* __restrict__ mem,
                 const float* __restrict__ ln1_w, const float* __restrict__ ln1_b,
                 const float* __restrict__ W_qkv, const float* __restrict__ b_qkv,
                 const float* __restrict__ W_out, const float* __restrict__ b_out,
                 const float* __restrict__ ln2_w, const float* __restrict__ ln2_b,
                 const float* __restrict__ ln3_w, const float* __restrict__ ln3_b,
                 const float* __restrict__ W_ff1, const float* __restrict__ b_ff1,
                 const float* __restrict__ ln4_w, const float* __restrict__ ln4_b,
                 const float* __restrict__ W_ff2, const float* __restrict__ b_ff2,
                 const float* __restrict__ ln5_w, const float* __restrict__ ln5_b,
                 const float* __restrict__ W_head, const float* __restrict__ b_head,
                 float* __restrict__ out)
{
    const int t    = threadIdx.x;
    const int b0   = blockIdx.x * Gn;
    const int lane = t & 63;
    const int wv   = t >> 6;

    // bf16 tile (32 KB), chunk-XOR swizzled; tail: float view (f1, partials, x)
    __shared__ __align__(16) unsigned short s16[Mn * Dn];
    __shared__ __align__(16) unsigned short s_At[Dn * Hn];   // A' bf16 [j][8]
    __shared__ __align__(16) float s_sc[Mn * 12];            // dots[8]+rstd per row; tail tmp
    __shared__ __align__(16) float s_u[Mn * 10];             // qw[r][10] -> ctxn[8][128]
    __shared__ __align__(16) float s_lnq[Dn];
    __shared__ __align__(16) float s_q[Dn];
    __shared__ __align__(16) float s_qin[Gn][Dn];
    __shared__ __align__(16) float s_hh[Gn][Dn];
    __shared__ __align__(16) float s_qo[Gn][Dn];
    __shared__ float s_s2c[Hn], s_s0[Hn], s_den[Hn], s_p0[Hn];

    float*  s16f  = (float*)s16;     // 8192 floats
    float4* s16f4 = (float4*)s16;

    //=== P0/P1: q_in = x @ W_in^T + b_in + pos (K-split-2, x staged) ======
    {
        const float4* src = (const float4*)(x + (size_t)b0 * DIN);
        s16f4[1024 + t]       = src[t];
        s16f4[1024 + 256 + t] = src[t + 256];
    }
    __syncthreads();
    {
        int d = t & 127, kg = t >> 7;
        const float4* w4 = (const float4*)(W_in + (size_t)d * DIN) + kg*64;
        float acc[4] = {0,0,0,0};
        for (int j = 0; j < 64; ++j) {
            float4 a = w4[j];
#pragma unroll
            for (int g = 0; g < 4; ++g) {
                float4 xv = s16f4[1024 + g*128 + kg*64 + j];
                acc[g] = fmaf(a.x, xv.x, acc[g]); acc[g] = fmaf(a.y, xv.y, acc[g]);
                acc[g] = fmaf(a.z, xv.z, acc[g]); acc[g] = fmaf(a.w, xv.w, acc[g]);
            }
        }
#pragma unroll
        for (int g = 0; g < 4; ++g) s16f[kg*512 + d*4 + g] = acc[g];
    }
    __syncthreads();
    {
#pragma unroll
        for (int u = 0; u < 2; ++u) {
            int idx = t*2 + u; int d = idx >> 2, g = idx & 3;
            float v = s16f[idx] + s16f[512 + idx];
            s_qin[g][d] = v + b_in[d] + pos[(size_t)(b0+g)*Dn + d];
        }
    }
    __syncthreads();

    //=== Attention: per batch ============================================
    for (int g = 0; g < Gn; ++g) {
        // S: stage tile as bf16, chunk-swizzled; wave0: lnq; waves 2-3: q
        {
            const float4* src = (const float4*)(mem + (size_t)(b0+g) * Mn * Dn);
#pragma unroll
            for (int i = 0; i < 16; ++i) {
                int fid = t + 256*i;
                float4 v = src[fid];
                int r = fid >> 5, k = fid & 31;
                int c = k >> 1, half = k & 1;
                unsigned u0 = pk_bf16(v.x, v.y), u1 = pk_bf16(v.z, v.w);
                *(uint2*)&s16[r*128 + ((c ^ (r & 7)) << 3) + half*4] = make_uint2(u0, u1);
            }
        }
        if (t < 64) {
            ln_row64<Dn>(&s_qin[g][0], s_lnq, ln1_w, ln1_b, nullptr, t);
        } else if (t >= 128) {
            int dd = t - 128;
            s_q[dd] = dot128(W_qkv + (size_t)dd*Dn, &s_qin[g][0]) + b_qkv[dd];
        }
        __syncthreads();

        // Aq: A' bf16 [j][8] (s1-folded) + per-head scalars s2c/s0
        {
            int h = t >> 5, js = t & 31;
            float aq[4] = {0,0,0,0};
            float ch = 0.f;
#pragma unroll
            for (int d0 = 0; d0 < 16; ++d0) {
                float qv = s_q[h*16 + d0];
                float4 w = ((const float4*)(W_qkv + (size_t)(Dn + h*16 + d0)*Dn))[js];
                aq[0] = fmaf(qv, w.x, aq[0]); aq[1] = fmaf(qv, w.y, aq[1]);
                aq[2] = fmaf(qv, w.z, aq[2]); aq[3] = fmaf(qv, w.w, aq[3]);
                ch = fmaf(qv, b_qkv[Dn + h*16 + d0], ch);
            }
            ch *= ATT_SCALE;
            float s1p = 0.f, s2p = 0.f, s0p = 0.f;
            float aqw[4];
#pragma unroll
            for (int c = 0; c < 4; ++c) {
                int j = js*4 + c;
                float a = ATT_SCALE * aq[c];
                aqw[c] = a * ln1_w[j];
                s1p += aqw[c];
                s2p = fmaf(a, ln1_b[j], s2p);
                s0p = fmaf(a, s_lnq[j], s0p);
            }
#pragma unroll
            for (int m = 16; m >= 1; m >>= 1) {
                s1p += __shfl_xor(s1p, m, 32);
                s2p += __shfl_xor(s2p, m, 32);
                s0p += __shfl_xor(s0p, m, 32);
            }
            float sub = s1p * (1.f/128.f);
#pragma unroll
            for (int c = 0; c < 4; ++c)
                s_At[(js*4 + c)*8 + h] = f2bf(aqw[c] - sub);
            if (js == 0) { s_s2c[h] = s2p + ch; s_s0[h] = s0p + ch; }
        }
        __syncthreads();

        // A: raw head-dots + row stats (2 lanes/row, bf16 b128 chunks)
        {
            int r = t >> 1, hf = t & 1;
            float d8[8] = {0,0,0,0,0,0,0,0};
            float sum = 0.f, ssq = 0.f;
#pragma unroll
            for (int kk = 0; kk < 8; ++kk) {
                int c = hf*8 + kk;
                uint4 tv = *(const uint4*)&s16[r*128 + ((c ^ (r & 7)) << 3)];
                float vv[8];
                vv[0] = lo16(tv.x); vv[1] = hi16(tv.x);
                vv[2] = lo16(tv.y); vv[3] = hi16(tv.y);
                vv[4] = lo16(tv.z); vv[5] = hi16(tv.z);
                vv[6] = lo16(tv.w); vv[7] = hi16(tv.w);
#pragma unroll
                for (int q = 0; q < 8; ++q) {
                    sum += vv[q];
                    ssq = fmaf(vv[q], vv[q], ssq);
                }
#pragma unroll
                for (int jj = 0; jj < 8; ++jj) {
                    int j = c*8 + jj;
                    uint4 au = *(const uint4*)&s_At[j*8];
                    float vj = vv[jj];
                    d8[0] = fmaf(lo16(au.x), vj, d8[0]);
                    d8[1] = fmaf(hi16(au.x), vj, d8[1]);
                    d8[2] = fmaf(lo16(au.y), vj, d8[2]);
                    d8[3] = fmaf(hi16(au.y), vj, d8[3]);
                    d8[4] = fmaf(lo16(au.z), vj, d8[4]);
                    d8[5] = fmaf(hi16(au.z), vj, d8[5]);
                    d8[6] = fmaf(lo16(au.w), vj, d8[6]);
                    d8[7] = fmaf(hi16(au.w), vj, d8[7]);
                }
            }
            sum += __shfl_xor(sum, 1);
            ssq += __shfl_xor(ssq, 1);
#pragma unroll
            for (int h = 0; h < 8; ++h) d8[h] += __shfl_xor(d8[h], 1);
            if (hf == 0) {
                float mean = sum * (1.f/128.f);
                float var  = fmaf(-mean, mean, ssq * (1.f/128.f));
                float rstd = rsqrtf(var + 1e-5f);
                *(float4*)&s_sc[r*12]     = make_float4(d8[0], d8[1], d8[2], d8[3]);
                *(float4*)&s_sc[r*12 + 4] = make_float4(d8[4], d8[5], d8[6], d8[7]);
                s_sc[r*12 + 8] = rstd;
            }
        }
        __syncthreads();

        // SM: one-shot softmax; wave w handles heads 2w,2w+1; lane l rows 2l,2l+1
        {
            int w = wv, l = lane;
            int h0 = 2*w, h1 = h0 + 1;
            int r0 = 2*l, r1 = r0 + 1;
            float2 da = *(const float2*)&s_sc[r0*12 + h0];
            float2 db = *(const float2*)&s_sc[r1*12 + h0];
            float rs0 = s_sc[r0*12 + 8], rs1 = s_sc[r1*12 + 8];
            float2 mk = *(const float2*)&mask[(size_t)(b0+g)*Mn + r0];
            float sc00 = fmaf(rs0, da.x, s_s2c[h0]) + mk.x;
            float sc01 = fmaf(rs0, da.y, s_s2c[h1]) + mk.x;
            float sc10 = fmaf(rs1, db.x, s_s2c[h0]) + mk.y;
            float sc11 = fmaf(rs1, db.y, s_s2c[h1]) + mk.y;
            float mx0 = fmaxf(sc00, sc10), mx1 = fmaxf(sc01, sc11);
#pragma unroll
            for (int m = 1; m < 64; m <<= 1) {
                mx0 = fmaxf(mx0, __shfl_xor(mx0, m));
                mx1 = fmaxf(mx1, __shfl_xor(mx1, m));
            }
            mx0 = fmaxf(mx0, s_s0[h0]);
            mx1 = fmaxf(mx1, s_s0[h1]);
            float e00 = __expf(sc00 - mx0), e10 = __expf(sc10 - mx0);
            float e01 = __expf(sc01 - mx1), e11 = __expf(sc11 - mx1);
            float ds0 = e00 + e10, ds1 = e01 + e11;
#pragma unroll
            for (int m = 1; m < 64; m <<= 1) {
                ds0 += __shfl_xor(ds0, m);
                ds1 += __shfl_xor(ds1, m);
            }
            float p00 = __expf(s_s0[h0] - mx0), p01 = __expf(s_s0[h1] - mx1);
            *(float2*)&s_u[r0*10 + h0] = make_float2(e00*rs0, e01*rs0);
            *(float2*)&s_u[r1*10 + h0] = make_float2(e10*rs1, e11*rs1);
            if (l == 0) {
                s_den[h0] = ds0 + p00; s_p0[h0] = p00;
                s_den[h1] = ds1 + p01; s_p0[h1] = p01;
            }
        }
        __syncthreads();

        // C: ctx (wave = head pair; quarter = 32 rows; lane chunk = 8 cols)
        float cx0[8], cx1[8], cS0, cS1;
        {
            int w = wv, l = lane;
            int qtr = l >> 4, c = l & 15;
#pragma unroll
            for (int q = 0; q < 8; ++q) { cx0[q] = 0.f; cx1[q] = 0.f; }
#pragma unroll 4
            for (int rr = 0; rr < 32; ++rr) {
                int r = qtr*32 + rr;
                uint4 tv = *(const uint4*)&s16[r*128 + ((c ^ (r & 7)) << 3)];
                float2 qv = *(const float2*)&s_u[r*10 + 2*w];
                float v0 = lo16(tv.x), v1 = hi16(tv.x);
                float v2 = lo16(tv.y), v3 = hi16(tv.y);
                float v4 = lo16(tv.z), v5 = hi16(tv.z);
                float v6 = lo16(tv.w), v7 = hi16(tv.w);
                cx0[0]=fmaf(qv.x,v0,cx0[0]); cx1[0]=fmaf(qv.y,v0,cx1[0]);
                cx0[1]=fmaf(qv.x,v1,cx0[1]); cx1[1]=fmaf(qv.y,v1,cx1[1]);
                cx0[2]=fmaf(qv.x,v2,cx0[2]); cx1[2]=fmaf(qv.y,v2,cx1[2]);
                cx0[3]=fmaf(qv.x,v3,cx0[3]); cx1[3]=fmaf(qv.y,v3,cx1[3]);
                cx0[4]=fmaf(qv.x,v4,cx0[4]); cx1[4]=fmaf(qv.y,v4,cx1[4]);
                cx0[5]=fmaf(qv.x,v5,cx0[5]); cx1[5]=fmaf(qv.y,v5,cx1[5]);
                cx0[6]=fmaf(qv.x,v6,cx0[6]); cx1[6]=fmaf(qv.y,v6,cx1[6]);
                cx0[7]=fmaf(qv.x,v7,cx0[7]); cx1[7]=fmaf(qv.y,v7,cx1[7]);
            }
            // combine the 4 row-quarters
#pragma unroll
            for (int q = 0; q < 8; ++q) {
                cx0[q] += __shfl_xor(cx0[q], 16);
                cx0[q] += __shfl_xor(cx0[q], 32);
                cx1[q] += __shfl_xor(cx1[q], 16);
                cx1[q] += __shfl_xor(cx1[q], 32);
            }
            // cS = sum_j ctx_raw / 128  (butterfly over the 16 chunks)
            float sA = ((cx0[0]+cx0[1])+(cx0[2]+cx0[3])) + ((cx0[4]+cx0[5])+(cx0[6]+cx0[7]));
            float sB = ((cx1[0]+cx1[1])+(cx1[2]+cx1[3])) + ((cx1[4]+cx1[5])+(cx1[6]+cx1[7]));
#pragma unroll
            for (int m = 1; m < 16; m <<= 1) {
                sA += __shfl_xor(sA, m);
                sB += __shfl_xor(sB, m);
            }
            cS0 = sA * (1.f/128.f);
            cS1 = sB * (1.f/128.f);
        }
        __syncthreads();   // all qw reads done before ctxn overwrites s_u

        // D: verified fold -> ctxn[8][128] into s_u (lanes 0..15 of each wave)
        if (lane < 16) {
            int c = lane;
            int h0 = 2*wv, h1 = h0 + 1;
            float den0 = s_den[h0], p0a = s_p0[h0], sP0 = den0 - p0a, inv0 = 1.f/den0;
            float den1 = s_den[h1], p0b = s_p0[h1], sP1 = den1 - p0b, inv1 = 1.f/den1;
#pragma unroll
            for (int q = 0; q < 2; ++q) {
                int j0 = c*8 + q*4;
                float4 lq = *(const float4*)&s_lnq[j0];
                float4 lw = *(const float4*)&ln1_w[j0];
                float4 lb = *(const float4*)&ln1_b[j0];
                float4 o0, o1;
                o0.x = (p0a*lq.x + lw.x*(cx0[q*4+0]-cS0) + lb.x*sP0) * inv0;
                o0.y = (p0a*lq.y + lw.y*(cx0[q*4+1]-cS0) + lb.y*sP0) * inv0;
                o0.z = (p0a*lq.z + lw.z*(cx0[q*4+2]-cS0) + lb.z*sP0) * inv0;
                o0.w = (p0a*lq.w + lw.w*(cx0[q*4+3]-cS0) + lb.w*sP0) * inv0;
                o1.x = (p0b*lq.x + lw.x*(cx1[q*4+0]-cS1) + lb.x*sP1) * inv1;
                o1.y = (p0b*lq.y + lw.y*(cx1[q*4+1]-cS1) + lb.y*sP1) * inv1;
                o1.z = (p0b*lq.z + lw.z*(cx1[q*4+2]-cS1) + lb.z*sP1) * inv1;
                o1.w = (p0b*lq.w + lw.w*(cx1[q*4+3]-cS1) + lb.w*sP1) * inv1;
                *(float4*)&s_u[h0*128 + j0] = o0;
                *(float4*)&s_u[h1*128 + j0] = o1;
            }
        }
        __syncthreads();

        // O: o = Wv @ ctxn + bv
        if (t < 128) {
            int h = t >> 4;
            s_qo[g][t] = dot128(W_qkv + (size_t)(2*Dn + t)*Dn, &s_u[h*128])
                       + b_qkv[2*Dn + t];
        }
        __syncthreads();
    }

    //=== Tail =============================================================
    // P6a: t1 = o @ W_out^T + b_out  (2 batches per thread-half)
    {
        int d = t & 127, gp = t >> 7;
        const float4* w4 = (const float4*)(W_out + (size_t)d * Dn);
        float a0 = 0.f, a1 = 0.f;
#pragma unroll 8
        for (int j = 0; j < 32; ++j) {
            float4 a = w4[j];
            float4 v0 = *(const float4*)&s_qo[2*gp][j*4];
            float4 v1 = *(const float4*)&s_qo[2*gp+1][j*4];
            a0 = fmaf(a.x,v0.x,a0); a0 = fmaf(a.y,v0.y,a0);
            a0 = fmaf(a.z,v0.z,a0); a0 = fmaf(a.w,v0.w,a0);
            a1 = fmaf(a.x,v1.x,a1); a1 = fmaf(a.y,v1.y,a1);
            a1 = fmaf(a.z,v1.z,a1); a1 = fmaf(a.w,v1.w,a1);
        }
        s_sc[(2*gp)*128 + d]   = a0 + b_out[d];
        s_sc[(2*gp+1)*128 + d] = a1 + b_out[d];
    }
    __syncthreads();

    // P6b: h = LN(t1, ln2) + q_in -> s_hh
    ln_row64<Dn>(&s_sc[wv*128], &s_hh[wv][0], ln2_w, ln2_b, &s_qin[wv][0], lane);
    __syncthreads();
    // P6c: ln3h = LN(h, ln3) -> s_qin
    ln_row64<Dn>(&s_hh[wv][0], &s_qin[wv][0], ln3_w, ln3_b, nullptr, lane);
    __syncthreads();

    // P6d: f1 = gelu(ln3h @ W_ff1^T + b_ff1) -> s16f[g*512 + e]
    {
        int e0 = t, e1 = t + 256;
        const float4* wa = (const float4*)(W_ff1 + (size_t)e0 * Dn);
        const float4* wb = (const float4*)(W_ff1 + (size_t)e1 * Dn);
        float acc0[4] = {0,0,0,0}, acc1[4] = {0,0,0,0};
#pragma unroll 4
        for (int j = 0; j < 32; ++j) {
            float4 a = wa[j], b = wb[j];
#pragma unroll
            for (int g2 = 0; g2 < 4; ++g2) {
                float4 v = *(const float4*)&s_qin[g2][j*4];
                acc0[g2] = fmaf(a.x,v.x,acc0[g2]); acc0[g2] = fmaf(a.y,v.y,acc0[g2]);
                acc0[g2] = fmaf(a.z,v.z,acc0[g2]); acc0[g2] = fmaf(a.w,v.w,acc0[g2]);
                acc1[g2] = fmaf(b.x,v.x,acc1[g2]); acc1[g2] = fmaf(b.y,v.y,acc1[g2]);
                acc1[g2] = fmaf(b.z,v.z,acc1[g2]); acc1[g2] = fmaf(b.w,v.w,acc1[g2]);
            }
        }
#pragma unroll
        for (int g2 = 0; g2 < 4; ++g2) {
            float v0 = acc0[g2] + b_ff1[e0];
            float v1 = acc1[g2] + b_ff1[e1];
            s16f[g2*512 + e0] = 0.5f * v0 * (1.f + erff(v0 * INV_SQRT2));
            s16f[g2*512 + e1] = 0.5f * v1 * (1.f + erff(v1 * INV_SQRT2));
        }
    }
    __syncthreads();

    // P6e: LN(f1, ln4) in place
    ln_row64<DFF>(&s16f[wv*512], &s16f[wv*512], ln4_w, ln4_b, nullptr, lane);
    __syncthreads();

    // P6f: f2 = f1 @ W_ff2^T (K-split-2) + b_ff2 + h -> s_sc
    {
        int d = t & 127, kg = t >> 7;
        const float4* w4 = (const float4*)(W_ff2 + (size_t)d * DFF) + kg*64;
        float acc[4] = {0,0,0,0};
        for (int j = 0; j < 64; ++j) {
            float4 a = w4[j];
#pragma unroll
            for (int g2 = 0; g2 < 4; ++g2) {
                float4 v = *(const float4*)&s16f[g2*512 + (kg*64 + j)*4];
                acc[g2] = fmaf(a.x,v.x,acc[g2]); acc[g2] = fmaf(a.y,v.y,acc[g2]);
                acc[g2] = fmaf(a.z,v.z,acc[g2]); acc[g2] = fmaf(a.w,v.w,acc[g2]);
            }
        }
#pragma unroll
        for (int g2 = 0; g2 < 4; ++g2) s16f[4096 + kg*512 + d*4 + g2] = acc[g2];
    }
    __syncthreads();
    {
#pragma unroll
        for (int u = 0; u < 2; ++u) {
            int idx = t*2 + u; int d = idx >> 2, g2 = idx & 3;
            float v = s16f[4096 + idx] + s16f[4608 + idx];
            s_sc[g2*128 + d] = v + b_ff2[d] + s_hh[g2][d];
        }
    }
    __syncthreads();

    // P6g: h2 = LN(ln5) -> s_qin
    ln_row64<Dn>(&s_sc[wv*128], &s_qin[wv][0], ln5_w, ln5_b, nullptr, lane);
    __syncthreads();

    // P6h: out = h2 @ W_head^T + b_head
    {
        int e0 = t, e1 = t + 256;
        const float4* wa = (const float4*)(W_head + (size_t)e0 * Dn);
        const float4* wb = (const float4*)(W_head + (size_t)e1 * Dn);
        float acc0[4] = {0,0,0,0}, acc1[4] = {0,0,0,0};
#pragma unroll 4
        for (int j = 0; j < 32; ++j) {
            float4 a = wa[j], b = wb[j];
#pragma unroll
            for (int g2 = 0; g2 < 4; ++g2) {
                float4 v = *(const float4*)&s_qin[g2][j*4];
                acc0[g2] = fmaf(a.x,v.x,acc0[g2]); acc0[g2] = fmaf(a.y,v.y,acc0[g2]);
                acc0[g2] = fmaf(a.z,v.z,acc0[g2]); acc0[g2] = fmaf(a.w,v.w,acc0[g2]);
                acc1[g2] = fmaf(b.x,v.x,acc1[g2]); acc1[g2] = fmaf(b.y,v.y,acc1[g2]);
                acc1[g2] = fmaf(b.z,v.z,acc1[g2]); acc1[g2] = fmaf(b.w,v.w,acc1[g2]);
            }
        }
#pragma unroll
        for (int g2 = 0; g2 < 4; ++g2) {
            out[(size_t)(b0+g2)*DIN + e0] = acc0[g2] + b_head[e0];
            out[(size_t)(b0+g2)*DIN + e1] = acc1[g2] + b_head[e1];
        }
    }
}

} // namespace

extern "C" void kernel_launch(void* const* d_in, const int* in_sizes, int n_in,
                              void* d_out, int out_size, void* d_ws, size_t ws_size,
                              hipStream_t stream)
{
    const float* x      = (const float*)d_in[0];
    const float* W_in   = (const float*)d_in[1];
    const float* b_in   = (const float*)d_in[2];
    const float* pos    = (const float*)d_in[3];
    const float* mask   = (const float*)d_in[4];
    const float* mem    = (const float*)d_in[5];
    const float* ln1_w  = (const float*)d_in[6];
    const float* ln1_b  = (const float*)d_in[7];
    const float* W_qkv  = (const float*)d_in[8];
    const float* b_qkv  = (const float*)d_in[9];
    const float* W_out  = (const float*)d_in[10];
    const float* b_out  = (const float*)d_in[11];
    const float* ln2_w  = (const float*)d_in[12];
    const float* ln2_b  = (const float*)d_in[13];
    const float* ln3_w  = (const float*)d_in[14];
    const float* ln3_b  = (const float*)d_in[15];
    const float* W_ff1  = (const float*)d_in[16];
    const float* b_ff1  = (const float*)d_in[17];
    const float* ln4_w  = (const float*)d_in[18];
    const float* ln4_b  = (const float*)d_in[19];
    const float* W_ff2  = (const float*)d_in[20];
    const float* b_ff2  = (const float*)d_in[21];
    const float* ln5_w  = (const float*)d_in[22];
    const float* ln5_b  = (const float*)d_in[23];
    const float* W_head = (const float*)d_in[24];
    const float* b_head = (const float*)d_in[25];

    const int B = in_sizes[0] / DIN;   // 4096
    fused_block<<<dim3(B / Gn), dim3(256), 0, stream>>>(
        x, W_in, b_in, pos, mask, mem,
        ln1_w, ln1_b, W_qkv, b_qkv, W_out, b_out,
        ln2_w, ln2_b, ln3_w, ln3_b,
        W_ff1, b_ff1, ln4_w, ln4_b, W_ff2, b_ff2,
        ln5_w, ln5_b, W_head, b_head,
        (float*)d_out);
}

// Round 8
// 329.714 us; speedup vs baseline: 1.4415x; 1.4415x over previous
//
#include <hip/hip_runtime.h>

namespace {

constexpr int Dn   = 128;
constexpr int DIN  = 512;
constexpr int Hn   = 8;
constexpr int Mn   = 128;
constexpr int DFF  = 512;
constexpr int Gn   = 4;     // batches per block (attention sequential per batch)
constexpr float ATT_SCALE = 0.25f;
constexpr float INV_SQRT2 = 0.70710678118654752440f;

__device__ __forceinline__ unsigned short f2bf(float f) {
    unsigned u = __float_as_uint(f);
    return (unsigned short)((u + 0x7fffu + ((u >> 16) & 1u)) >> 16);
}
__device__ __forceinline__ unsigned pk_bf16(float lo, float hi) {
    unsigned r;
    asm volatile("v_cvt_pk_bf16_f32 %0, %1, %2" : "=v"(r) : "v"(lo), "v"(hi));
    return r;
}
__device__ __forceinline__ float lo16(unsigned u) { return __uint_as_float(u << 16); }
__device__ __forceinline__ float hi16(unsigned u) { return __uint_as_float(u & 0xffff0000u); }

// dot of a 128-float global row with a 128-float LDS vector (broadcast v)
__device__ __forceinline__ float dot128(const float* __restrict__ wrow,
                                        const float* __restrict__ v)
{
    const float4* w4 = (const float4*)wrow;
    const float4* v4 = (const float4*)v;
    float acc = 0.f;
#pragma unroll
    for (int j = 0; j < 32; ++j) {
        float4 a = w4[j], b = v4[j];
        acc += a.x*b.x + a.y*b.y + a.z*b.z + a.w*b.w;
    }
    return acc;
}

// LayerNorm, 64 threads per row (one wave). In-place safe.
template <int NCOL>
__device__ __forceinline__ void ln_row64(const float* __restrict__ src,
                                         float* __restrict__ dst,
                                         const float* __restrict__ gw,
                                         const float* __restrict__ gb,
                                         const float* __restrict__ resid,
                                         int sub)
{
    constexpr int E = NCOL / 64;
    float v0[E]; float sm = 0.f;
#pragma unroll
    for (int i = 0; i < E; ++i) { v0[i] = src[sub*E + i]; sm += v0[i]; }
#pragma unroll
    for (int m = 32; m >= 1; m >>= 1) sm += __shfl_xor(sm, m);
    float mean = sm * (1.f / (float)NCOL);
    float vs = 0.f;
#pragma unroll
    for (int i = 0; i < E; ++i) { float d0 = v0[i] - mean; vs += d0*d0; }
#pragma unroll
    for (int m = 32; m >= 1; m >>= 1) vs += __shfl_xor(vs, m);
    float rstd = rsqrtf(vs * (1.f / (float)NCOL) + 1e-5f);
#pragma unroll
    for (int i = 0; i < E; ++i) {
        int d = sub*E + i;
        float r = (v0[i] - mean) * rstd * gw[d] + gb[d];
        dst[d] = resid ? (r + resid[d]) : r;
    }
}

// NOTE: min-waves-per-EU >= 3 here makes the register allocator spill the
// attention accumulators to scratch (r3: 64 VGPR/267MB, r7: 84 VGPR/122MB).
// Keep (256,2); occupancy comes from the ~51KB LDS footprint (3 blocks/CU).
__global__ __launch_bounds__(256, 2)
void fused_block(const float* __restrict__ x,
                 const float* __restrict__ W_in,
                 const float* __restrict__ b_in,
                 const float* __restrict__ pos,
                 const float* __restrict__ mask,
                 const float* __restrict__ mem,
                 const float* __restrict__ ln1_w, const float* __restrict__ ln1_b,
                 const float* __restrict__ W_qkv, const float* __restrict__ b_qkv,
                 const float* __restrict__ W_out, const float* __restrict__ b_out,
                 const float* __restrict__ ln2_w, const float* __restrict__ ln2_b,
                 const float* __restrict__ ln3_w, const float* __restrict__ ln3_b,
                 const float* __restrict__ W_ff1, const float* __restrict__ b_ff1,
                 const float* __restrict__ ln4_w, const float* __restrict__ ln4_b,
                 const float* __restrict__ W_ff2, const float* __restrict__ b_ff2,
                 const float* __restrict__ ln5_w, const float* __restrict__ ln5_b,
                 const float* __restrict__ W_head, const float* __restrict__ b_head,
                 float* __restrict__ out)
{
    const int t    = threadIdx.x;
    const int b0   = blockIdx.x * Gn;
    const int lane = t & 63;
    const int wv   = t >> 6;

    // bf16 tile (32 KB), chunk-XOR swizzled; tail: float view (f1, partials, x)
    __shared__ __align__(16) unsigned short s16[Mn * Dn];
    __shared__ __align__(16) unsigned short s_At[Dn * Hn];   // A' bf16 [j][8]
    __shared__ __align__(16) float s_sc[Mn * 12];            // q -> dots[8]+rstd; tail tmp
    __shared__ __align__(16) float s_u[Mn * 10];             // qw[r][10] -> ctxn[8][128] -> h-resid
    __shared__ __align__(16) float s_lnq[Dn];
    __shared__ __align__(16) float s_qin[Gn][Dn];
    __shared__ __align__(16) float s_qo[Gn][Dn];
    __shared__ float s_s2c[Hn], s_s0[Hn], s_den[Hn], s_p0[Hn];

    float*  s16f  = (float*)s16;     // 8192 floats
    float4* s16f4 = (float4*)s16;
    float*  s_q   = s_sc;                         // alias: dead before Pass A writes
    float (*s_hh)[Dn] = (float(*)[Dn])s_u;        // alias: tail-only, s_u dead then

    //=== P0/P1: q_in = x @ W_in^T + b_in + pos (K-split-2, x staged) ======
    {
        const float4* src = (const float4*)(x + (size_t)b0 * DIN);
        s16f4[1024 + t]       = src[t];
        s16f4[1024 + 256 + t] = src[t + 256];
    }
    __syncthreads();
    {
        int d = t & 127, kg = t >> 7;
        const float4* w4 = (const float4*)(W_in + (size_t)d * DIN) + kg*64;
        float acc[4] = {0,0,0,0};
        for (int j = 0; j < 64; ++j) {
            float4 a = w4[j];
#pragma unroll
            for (int g = 0; g < 4; ++g) {
                float4 xv = s16f4[1024 + g*128 + kg*64 + j];
                acc[g] = fmaf(a.x, xv.x, acc[g]); acc[g] = fmaf(a.y, xv.y, acc[g]);
                acc[g] = fmaf(a.z, xv.z, acc[g]); acc[g] = fmaf(a.w, xv.w, acc[g]);
            }
        }
#pragma unroll
        for (int g = 0; g < 4; ++g) s16f[kg*512 + d*4 + g] = acc[g];
    }
    __syncthreads();
    {
#pragma unroll
        for (int u = 0; u < 2; ++u) {
            int idx = t*2 + u; int d = idx >> 2, g = idx & 3;
            float v = s16f[idx] + s16f[512 + idx];
            s_qin[g][d] = v + b_in[d] + pos[(size_t)(b0+g)*Dn + d];
        }
    }
    __syncthreads();

    //=== Attention: per batch ============================================
    for (int g = 0; g < Gn; ++g) {
        // S: stage tile as bf16, chunk-swizzled; wave0: lnq; waves 2-3: q
        {
            const float4* src = (const float4*)(mem + (size_t)(b0+g) * Mn * Dn);
#pragma unroll
            for (int i = 0; i < 16; ++i) {
                int fid = t + 256*i;
                float4 v = src[fid];
                int r = fid >> 5, k = fid & 31;
                int c = k >> 1, half = k & 1;
                unsigned u0 = pk_bf16(v.x, v.y), u1 = pk_bf16(v.z, v.w);
                *(uint2*)&s16[r*128 + ((c ^ (r & 7)) << 3) + half*4] = make_uint2(u0, u1);
            }
        }
        if (t < 64) {
            ln_row64<Dn>(&s_qin[g][0], s_lnq, ln1_w, ln1_b, nullptr, t);
        } else if (t >= 128) {
            int dd = t - 128;
            s_q[dd] = dot128(W_qkv + (size_t)dd*Dn, &s_qin[g][0]) + b_qkv[dd];
        }
        __syncthreads();

        // Aq: A' bf16 [j][8] (s1-folded) + per-head scalars s2c/s0
        {
            int h = t >> 5, js = t & 31;
            float aq[4] = {0,0,0,0};
            float ch = 0.f;
#pragma unroll
            for (int d0 = 0; d0 < 16; ++d0) {
                float qv = s_q[h*16 + d0];
                float4 w = ((const float4*)(W_qkv + (size_t)(Dn + h*16 + d0)*Dn))[js];
                aq[0] = fmaf(qv, w.x, aq[0]); aq[1] = fmaf(qv, w.y, aq[1]);
                aq[2] = fmaf(qv, w.z, aq[2]); aq[3] = fmaf(qv, w.w, aq[3]);
                ch = fmaf(qv, b_qkv[Dn + h*16 + d0], ch);
            }
            ch *= ATT_SCALE;
            float s1p = 0.f, s2p = 0.f, s0p = 0.f;
            float aqw[4];
#pragma unroll
            for (int c = 0; c < 4; ++c) {
                int j = js*4 + c;
                float a = ATT_SCALE * aq[c];
                aqw[c] = a * ln1_w[j];
                s1p += aqw[c];
                s2p = fmaf(a, ln1_b[j], s2p);
                s0p = fmaf(a, s_lnq[j], s0p);
            }
#pragma unroll
            for (int m = 16; m >= 1; m >>= 1) {
                s1p += __shfl_xor(s1p, m, 32);
                s2p += __shfl_xor(s2p, m, 32);
                s0p += __shfl_xor(s0p, m, 32);
            }
            float sub = s1p * (1.f/128.f);
#pragma unroll
            for (int c = 0; c < 4; ++c)
                s_At[(js*4 + c)*8 + h] = f2bf(aqw[c] - sub);
            if (js == 0) { s_s2c[h] = s2p + ch; s_s0[h] = s0p + ch; }
        }
        __syncthreads();

        // A: raw head-dots + row stats (2 lanes/row, bf16 b128 chunks)
        {
            int r = t >> 1, hf = t & 1;
            float d8[8] = {0,0,0,0,0,0,0,0};
            float sum = 0.f, ssq = 0.f;
#pragma unroll
            for (int kk = 0; kk < 8; ++kk) {
                int c = hf*8 + kk;
                uint4 tv = *(const uint4*)&s16[r*128 + ((c ^ (r & 7)) << 3)];
                float vv[8];
                vv[0] = lo16(tv.x); vv[1] = hi16(tv.x);
                vv[2] = lo16(tv.y); vv[3] = hi16(tv.y);
                vv[4] = lo16(tv.z); vv[5] = hi16(tv.z);
                vv[6] = lo16(tv.w); vv[7] = hi16(tv.w);
#pragma unroll
                for (int q = 0; q < 8; ++q) {
                    sum += vv[q];
                    ssq = fmaf(vv[q], vv[q], ssq);
                }
#pragma unroll
                for (int jj = 0; jj < 8; ++jj) {
                    int j = c*8 + jj;
                    uint4 au = *(const uint4*)&s_At[j*8];
                    float vj = vv[jj];
                    d8[0] = fmaf(lo16(au.x), vj, d8[0]);
                    d8[1] = fmaf(hi16(au.x), vj, d8[1]);
                    d8[2] = fmaf(lo16(au.y), vj, d8[2]);
                    d8[3] = fmaf(hi16(au.y), vj, d8[3]);
                    d8[4] = fmaf(lo16(au.z), vj, d8[4]);
                    d8[5] = fmaf(hi16(au.z), vj, d8[5]);
                    d8[6] = fmaf(lo16(au.w), vj, d8[6]);
                    d8[7] = fmaf(hi16(au.w), vj, d8[7]);
                }
            }
            sum += __shfl_xor(sum, 1);
            ssq += __shfl_xor(ssq, 1);
#pragma unroll
            for (int h = 0; h < 8; ++h) d8[h] += __shfl_xor(d8[h], 1);
            if (hf == 0) {
                float mean = sum * (1.f/128.f);
                float var  = fmaf(-mean, mean, ssq * (1.f/128.f));
                float rstd = rsqrtf(var + 1e-5f);
                *(float4*)&s_sc[r*12]     = make_float4(d8[0], d8[1], d8[2], d8[3]);
                *(float4*)&s_sc[r*12 + 4] = make_float4(d8[4], d8[5], d8[6], d8[7]);
                s_sc[r*12 + 8] = rstd;
            }
        }
        __syncthreads();

        // SM: one-shot softmax; wave w handles heads 2w,2w+1; lane l rows 2l,2l+1
        {
            int w = wv, l = lane;
            int h0 = 2*w, h1 = h0 + 1;
            int r0 = 2*l, r1 = r0 + 1;
            float2 da = *(const float2*)&s_sc[r0*12 + h0];
            float2 db = *(const float2*)&s_sc[r1*12 + h0];
            float rs0 = s_sc[r0*12 + 8], rs1 = s_sc[r1*12 + 8];
            float2 mk = *(const float2*)&mask[(size_t)(b0+g)*Mn + r0];
            float sc00 = fmaf(rs0, da.x, s_s2c[h0]) + mk.x;
            float sc01 = fmaf(rs0, da.y, s_s2c[h1]) + mk.x;
            float sc10 = fmaf(rs1, db.x, s_s2c[h0]) + mk.y;
            float sc11 = fmaf(rs1, db.y, s_s2c[h1]) + mk.y;
            float mx0 = fmaxf(sc00, sc10), mx1 = fmaxf(sc01, sc11);
#pragma unroll
            for (int m = 1; m < 64; m <<= 1) {
                mx0 = fmaxf(mx0, __shfl_xor(mx0, m));
                mx1 = fmaxf(mx1, __shfl_xor(mx1, m));
            }
            mx0 = fmaxf(mx0, s_s0[h0]);
            mx1 = fmaxf(mx1, s_s0[h1]);
            float e00 = __expf(sc00 - mx0), e10 = __expf(sc10 - mx0);
            float e01 = __expf(sc01 - mx1), e11 = __expf(sc11 - mx1);
            float ds0 = e00 + e10, ds1 = e01 + e11;
#pragma unroll
            for (int m = 1; m < 64; m <<= 1) {
                ds0 += __shfl_xor(ds0, m);
                ds1 += __shfl_xor(ds1, m);
            }
            float p00 = __expf(s_s0[h0] - mx0), p01 = __expf(s_s0[h1] - mx1);
            *(float2*)&s_u[r0*10 + h0] = make_float2(e00*rs0, e01*rs0);
            *(float2*)&s_u[r1*10 + h0] = make_float2(e10*rs1, e11*rs1);
            if (l == 0) {
                s_den[h0] = ds0 + p00; s_p0[h0] = p00;
                s_den[h1] = ds1 + p01; s_p0[h1] = p01;
            }
        }
        __syncthreads();

        // C: ctx (wave = head pair; quarter = 32 rows; lane chunk = 8 cols)
        float cx0[8], cx1[8], cS0, cS1;
        {
            int w = wv, l = lane;
            int qtr = l >> 4, c = l & 15;
#pragma unroll
            for (int q = 0; q < 8; ++q) { cx0[q] = 0.f; cx1[q] = 0.f; }
#pragma unroll 4
            for (int rr = 0; rr < 32; ++rr) {
                int r = qtr*32 + rr;
                uint4 tv = *(const uint4*)&s16[r*128 + ((c ^ (r & 7)) << 3)];
                float2 qv = *(const float2*)&s_u[r*10 + 2*w];
                float v0 = lo16(tv.x), v1 = hi16(tv.x);
                float v2 = lo16(tv.y), v3 = hi16(tv.y);
                float v4 = lo16(tv.z), v5 = hi16(tv.z);
                float v6 = lo16(tv.w), v7 = hi16(tv.w);
                cx0[0]=fmaf(qv.x,v0,cx0[0]); cx1[0]=fmaf(qv.y,v0,cx1[0]);
                cx0[1]=fmaf(qv.x,v1,cx0[1]); cx1[1]=fmaf(qv.y,v1,cx1[1]);
                cx0[2]=fmaf(qv.x,v2,cx0[2]); cx1[2]=fmaf(qv.y,v2,cx1[2]);
                cx0[3]=fmaf(qv.x,v3,cx0[3]); cx1[3]=fmaf(qv.y,v3,cx1[3]);
                cx0[4]=fmaf(qv.x,v4,cx0[4]); cx1[4]=fmaf(qv.y,v4,cx1[4]);
                cx0[5]=fmaf(qv.x,v5,cx0[5]); cx1[5]=fmaf(qv.y,v5,cx1[5]);
                cx0[6]=fmaf(qv.x,v6,cx0[6]); cx1[6]=fmaf(qv.y,v6,cx1[6]);
                cx0[7]=fmaf(qv.x,v7,cx0[7]); cx1[7]=fmaf(qv.y,v7,cx1[7]);
            }
            // combine the 4 row-quarters
#pragma unroll
            for (int q = 0; q < 8; ++q) {
                cx0[q] += __shfl_xor(cx0[q], 16);
                cx0[q] += __shfl_xor(cx0[q], 32);
                cx1[q] += __shfl_xor(cx1[q], 16);
                cx1[q] += __shfl_xor(cx1[q], 32);
            }
            // cS = sum_j ctx_raw / 128  (butterfly over the 16 chunks)
            float sA = ((cx0[0]+cx0[1])+(cx0[2]+cx0[3])) + ((cx0[4]+cx0[5])+(cx0[6]+cx0[7]));
            float sB = ((cx1[0]+cx1[1])+(cx1[2]+cx1[3])) + ((cx1[4]+cx1[5])+(cx1[6]+cx1[7]));
#pragma unroll
            for (int m = 1; m < 16; m <<= 1) {
                sA += __shfl_xor(sA, m);
                sB += __shfl_xor(sB, m);
            }
            cS0 = sA * (1.f/128.f);
            cS1 = sB * (1.f/128.f);
        }
        __syncthreads();   // all qw reads done before ctxn overwrites s_u

        // D: verified fold -> ctxn[8][128] into s_u (lanes 0..15 of each wave)
        if (lane < 16) {
            int c = lane;
            int h0 = 2*wv, h1 = h0 + 1;
            float den0 = s_den[h0], p0a = s_p0[h0], sP0 = den0 - p0a, inv0 = 1.f/den0;
            float den1 = s_den[h1], p0b = s_p0[h1], sP1 = den1 - p0b, inv1 = 1.f/den1;
#pragma unroll
            for (int q = 0; q < 2; ++q) {
                int j0 = c*8 + q*4;
                float4 lq = *(const float4*)&s_lnq[j0];
                float4 lw = *(const float4*)&ln1_w[j0];
                float4 lb = *(const float4*)&ln1_b[j0];
                float4 o0, o1;
                o0.x = (p0a*lq.x + lw.x*(cx0[q*4+0]-cS0) + lb.x*sP0) * inv0;
                o0.y = (p0a*lq.y + lw.y*(cx0[q*4+1]-cS0) + lb.y*sP0) * inv0;
                o0.z = (p0a*lq.z + lw.z*(cx0[q*4+2]-cS0) + lb.z*sP0) * inv0;
                o0.w = (p0a*lq.w + lw.w*(cx0[q*4+3]-cS0) + lb.w*sP0) * inv0;
                o1.x = (p0b*lq.x + lw.x*(cx1[q*4+0]-cS1) + lb.x*sP1) * inv1;
                o1.y = (p0b*lq.y + lw.y*(cx1[q*4+1]-cS1) + lb.y*sP1) * inv1;
                o1.z = (p0b*lq.z + lw.z*(cx1[q*4+2]-cS1) + lb.z*sP1) * inv1;
                o1.w = (p0b*lq.w + lw.w*(cx1[q*4+3]-cS1) + lb.w*sP1) * inv1;
                *(float4*)&s_u[h0*128 + j0] = o0;
                *(float4*)&s_u[h1*128 + j0] = o1;
            }
        }
        __syncthreads();

        // O: o = Wv @ ctxn + bv
        if (t < 128) {
            int h = t >> 4;
            s_qo[g][t] = dot128(W_qkv + (size_t)(2*Dn + t)*Dn, &s_u[h*128])
                       + b_qkv[2*Dn + t];
        }
        __syncthreads();
    }

    //=== Tail =============================================================
    // P6a: t1 = o @ W_out^T + b_out  (2 batches per thread-half)
    {
        int d = t & 127, gp = t >> 7;
        const float4* w4 = (const float4*)(W_out + (size_t)d * Dn);
        float a0 = 0.f, a1 = 0.f;
#pragma unroll 8
        for (int j = 0; j < 32; ++j) {
            float4 a = w4[j];
            float4 v0 = *(const float4*)&s_qo[2*gp][j*4];
            float4 v1 = *(const float4*)&s_qo[2*gp+1][j*4];
            a0 = fmaf(a.x,v0.x,a0); a0 = fmaf(a.y,v0.y,a0);
            a0 = fmaf(a.z,v0.z,a0); a0 = fmaf(a.w,v0.w,a0);
            a1 = fmaf(a.x,v1.x,a1); a1 = fmaf(a.y,v1.y,a1);
            a1 = fmaf(a.z,v1.z,a1); a1 = fmaf(a.w,v1.w,a1);
        }
        s_sc[(2*gp)*128 + d]   = a0 + b_out[d];
        s_sc[(2*gp+1)*128 + d] = a1 + b_out[d];
    }
    __syncthreads();

    // P6b: h = LN(t1, ln2) + q_in -> s_hh (aliases s_u; attention done)
    ln_row64<Dn>(&s_sc[wv*128], &s_hh[wv][0], ln2_w, ln2_b, &s_qin[wv][0], lane);
    __syncthreads();
    // P6c: ln3h = LN(h, ln3) -> s_qin
    ln_row64<Dn>(&s_hh[wv][0], &s_qin[wv][0], ln3_w, ln3_b, nullptr, lane);
    __syncthreads();

    // P6d: f1 = gelu(ln3h @ W_ff1^T + b_ff1) -> s16f[g*512 + e]
    {
        int e0 = t, e1 = t + 256;
        const float4* wa = (const float4*)(W_ff1 + (size_t)e0 * Dn);
        const float4* wb = (const float4*)(W_ff1 + (size_t)e1 * Dn);
        float acc0[4] = {0,0,0,0}, acc1[4] = {0,0,0,0};
#pragma unroll 4
        for (int j = 0; j < 32; ++j) {
            float4 a = wa[j], b = wb[j];
#pragma unroll
            for (int g2 = 0; g2 < 4; ++g2) {
                float4 v = *(const float4*)&s_qin[g2][j*4];
                acc0[g2] = fmaf(a.x,v.x,acc0[g2]); acc0[g2] = fmaf(a.y,v.y,acc0[g2]);
                acc0[g2] = fmaf(a.z,v.z,acc0[g2]); acc0[g2] = fmaf(a.w,v.w,acc0[g2]);
                acc1[g2] = fmaf(b.x,v.x,acc1[g2]); acc1[g2] = fmaf(b.y,v.y,acc1[g2]);
                acc1[g2] = fmaf(b.z,v.z,acc1[g2]); acc1[g2] = fmaf(b.w,v.w,acc1[g2]);
            }
        }
#pragma unroll
        for (int g2 = 0; g2 < 4; ++g2) {
            float v0 = acc0[g2] + b_ff1[e0];
            float v1 = acc1[g2] + b_ff1[e1];
            s16f[g2*512 + e0] = 0.5f * v0 * (1.f + erff(v0 * INV_SQRT2));
            s16f[g2*512 + e1] = 0.5f * v1 * (1.f + erff(v1 * INV_SQRT2));
        }
    }
    __syncthreads();

    // P6e: LN(f1, ln4) in place
    ln_row64<DFF>(&s16f[wv*512], &s16f[wv*512], ln4_w, ln4_b, nullptr, lane);
    __syncthreads();

    // P6f: f2 = f1 @ W_ff2^T (K-split-2) + b_ff2 + h -> s_sc
    {
        int d = t & 127, kg = t >> 7;
        const float4* w4 = (const float4*)(W_ff2 + (size_t)d * DFF) + kg*64;
        float acc[4] = {0,0,0,0};
        for (int j = 0; j < 64; ++j) {
            float4 a = w4[j];
#pragma unroll
            for (int g2 = 0; g2 < 4; ++g2) {
                float4 v = *(const float4*)&s16f[g2*512 + (kg*64 + j)*4];
                acc[g2] = fmaf(a.x,v.x,acc[g2]); acc[g2] = fmaf(a.y,v.y,acc[g2]);
                acc[g2] = fmaf(a.z,v.z,acc[g2]); acc[g2] = fmaf(a.w,v.w,acc[g2]);
            }
        }
#pragma unroll
        for (int g2 = 0; g2 < 4; ++g2) s16f[4096 + kg*512 + d*4 + g2] = acc[g2];
    }
    __syncthreads();
    {
#pragma unroll
        for (int u = 0; u < 2; ++u) {
            int idx = t*2 + u; int d = idx >> 2, g2 = idx & 3;
            float v = s16f[4096 + idx] + s16f[4608 + idx];
            s_sc[g2*128 + d] = v + b_ff2[d] + s_hh[g2][d];
        }
    }
    __syncthreads();

    // P6g: h2 = LN(ln5) -> s_qin
    ln_row64<Dn>(&s_sc[wv*128], &s_qin[wv][0], ln5_w, ln5_b, nullptr, lane);
    __syncthreads();

    // P6h: out = h2 @ W_head^T + b_head
    {
        int e0 = t, e1 = t + 256;
        const float4* wa = (const float4*)(W_head + (size_t)e0 * Dn);
        const float4* wb = (const float4*)(W_head + (size_t)e1 * Dn);
        float acc0[4] = {0,0,0,0}, acc1[4] = {0,0,0,0};
#pragma unroll 4
        for (int j = 0; j < 32; ++j) {
            float4 a = wa[j], b = wb[j];
#pragma unroll
            for (int g2 = 0; g2 < 4; ++g2) {
                float4 v = *(const float4*)&s_qin[g2][j*4];
                acc0[g2] = fmaf(a.x,v.x,acc0[g2]); acc0[g2] = fmaf(a.y,v.y,acc0[g2]);
                acc0[g2] = fmaf(a.z,v.z,acc0[g2]); acc0[g2] = fmaf(a.w,v.w,acc0[g2]);
                acc1[g2] = fmaf(b.x,v.x,acc1[g2]); acc1[g2] = fmaf(b.y,v.y,acc1[g2]);
                acc1[g2] = fmaf(b.z,v.z,acc1[g2]); acc1[g2] = fmaf(b.w,v.w,acc1[g2]);
            }
        }
#pragma unroll
        for (int g2 = 0; g2 < 4; ++g2) {
            out[(size_t)(b0+g2)*DIN + e0] = acc0[g2] + b_head[e0];
            out[(size_t)(b0+g2)*DIN + e1] = acc1[g2] + b_head[e1];
        }
    }
}

} // namespace

extern "C" void kernel_launch(void* const* d_in, const int* in_sizes, int n_in,
                              void* d_out, int out_size, void* d_ws, size_t ws_size,
                              hipStream_t stream)
{
    const float* x      = (const float*)d_in[0];
    const float* W_in   = (const float*)d_in[1];
    const float* b_in   = (const float*)d_in[2];
    const float* pos    = (const float*)d_in[3];
    const float* mask   = (const float*)d_in[4];
    const float* mem    = (const float*)d_in[5];
    const float* ln1_w  = (const float*)d_in[6];
    const float* ln1_b  = (const float*)d_in[7];
    const float* W_qkv  = (const float*)d_in[8];
    const float* b_qkv  = (const float*)d_in[9];
    const float* W_out  = (const float*)d_in[10];
    const float* b_out  = (const float*)d_in[11];
    const float* ln2_w  = (const float*)d_in[12];
    const float* ln2_b  = (const float*)d_in[13];
    const float* ln3_w  = (const float*)d_in[14];
    const float* ln3_b  = (const float*)d_in[15];
    const float* W_ff1  = (const float*)d_in[16];
    const float* b_ff1  = (const float*)d_in[17];
    const float* ln4_w  = (const float*)d_in[18];
    const float* ln4_b  = (const float*)d_in[19];
    const float* W_ff2  = (const float*)d_in[20];
    const float* b_ff2  = (const float*)d_in[21];
    const float* ln5_w  = (const float*)d_in[22];
    const float* ln5_b  = (const float*)d_in[23];
    const float* W_head = (const float*)d_in[24];
    const float* b_head = (const float*)d_in[25];

    const int B = in_sizes[0] / DIN;   // 4096
    fused_block<<<dim3(B / Gn), dim3(256), 0, stream>>>(
        x, W_in, b_in, pos, mask, mem,
        ln1_w, ln1_b, W_qkv, b_qkv, W_out, b_out,
        ln2_w, ln2_b, ln3_w, ln3_b,
        W_ff1, b_ff1, ln4_w, ln4_b, W_ff2, b_ff2,
        ln5_w, ln5_b, W_head, b_head,
        (float*)d_out);
}